// Round 17
// baseline (369.774 us; speedup 1.0000x reference)
//
#include <hip/hip_runtime.h>
#include <hip/hip_bf16.h>
#include <cstdint>
#include <cstddef>

typedef __bf16 bf16x8 __attribute__((ext_vector_type(8)));
typedef float f32x4 __attribute__((ext_vector_type(4)));

#define MOD_SCALE 1.4731391e-02f   // 1/sqrt(512*9)
#define EPSF 1e-8f

// ---------------------------------------------------------------------------
// K1: s[b][i] = dot(style[b], mod_w[i]) + mod_b[i]   (grid 16b x 8ig, 64 thr)
// ---------------------------------------------------------------------------
__global__ __launch_bounds__(64) void k_style(
    const float* __restrict__ style, const float* __restrict__ mod_w,
    const float* __restrict__ mod_b, float* __restrict__ s)
{
  __shared__ float st[512];
  const int b = blockIdx.x >> 3, ig = blockIdx.x & 7;
  const int t = threadIdx.x;
  for (int k = t; k < 512; k += 64) st[k] = style[b*512 + k];
  __syncthreads();
  const int i = ig*64 + t;
  const float4* mw = (const float4*)(mod_w + (size_t)i*512);
  float acc = 0.f;
  #pragma unroll 8
  for (int j = 0; j < 128; ++j) {
    float4 v = mw[j];
    acc += v.x*st[4*j] + v.y*st[4*j+1] + v.z*st[4*j+2] + v.w*st[4*j+3];
  }
  s[b*512 + i] = acc + mod_b[i];
}

// ---------------------------------------------------------------------------
// K2: w2[o][i] = sum_kk weight^2 ; Wb[kk][o][i] = bf16(SCALE*weight)
// ---------------------------------------------------------------------------
__global__ __launch_bounds__(256) void k_weight(
    const float* __restrict__ weight, float* __restrict__ w2,
    __hip_bfloat16* __restrict__ Wb)
{
  const int o = blockIdx.x, t = threadIdx.x;
  #pragma unroll
  for (int h = 0; h < 2; ++h) {
    const int i = t + h*256;
    const float* wp = weight + ((size_t)o*512 + i)*9;
    float sq = 0.f;
    #pragma unroll
    for (int kk = 0; kk < 9; ++kk) {
      float v = wp[kk];
      sq += v*v;
      Wb[((size_t)kk*512 + o)*512 + i] = __float2bfloat16(v * MOD_SCALE);
    }
    w2[(size_t)o*512 + i] = sq;
  }
}

// ---------------------------------------------------------------------------
// K2b: demod[b][o] = rsqrt(...)   (grid 16b x 8og, 64 thr)
// ---------------------------------------------------------------------------
__global__ __launch_bounds__(64) void k_demod(
    const float* __restrict__ s, const float* __restrict__ w2,
    float* __restrict__ demod)
{
  __shared__ float s2[512];
  const int b = blockIdx.x >> 3, og = blockIdx.x & 7;
  const int t = threadIdx.x;
  for (int k = t; k < 512; k += 64) { float a = s[b*512 + k]; s2[k] = a*a; }
  __syncthreads();
  const int o = og*64 + t;
  const float4* wp = (const float4*)(w2 + (size_t)o*512);
  float acc = 0.f;
  #pragma unroll 8
  for (int j = 0; j < 128; ++j) {
    float4 v = wp[j];
    acc += v.x*s2[4*j] + v.y*s2[4*j+1] + v.z*s2[4*j+2] + v.w*s2[4*j+3];
  }
  demod[b*512 + o] = rsqrtf(MOD_SCALE*MOD_SCALE*acc + EPSF);
}

// ---------------------------------------------------------------------------
// K3: Xm[b][py][px][i] = bf16(s[b][i]*x[b][i][py-1][px-1]); writes own halo.
// ---------------------------------------------------------------------------
__global__ __launch_bounds__(256) void k_xm(
    const float* __restrict__ x, const float* __restrict__ s,
    __hip_bfloat16* __restrict__ Xm)
{
  __shared__ __hip_bfloat16 T[64][72];   // [ch][px], stride 144B
  const int bid = blockIdx.x;
  const int cb = bid & 7, y = (bid >> 3) & 63, b = bid >> 9;
  const int ic0 = cb*64;
  const int t = threadIdx.x;
  const int i = t >> 2;            // ch 0..63
  const int q = t & 3;             // px quarter
  const int x0 = q*16;
  const float sv = s[b*512 + ic0 + i];
  const float4* xp = (const float4*)(x + (size_t)(b*512 + ic0 + i)*4096 + y*64 + x0);
  float4 v[4] = {xp[0], xp[1], xp[2], xp[3]};
  __hip_bfloat16 tmp[16];
  #pragma unroll
  for (int j = 0; j < 4; ++j) {
    tmp[4*j+0] = __float2bfloat16(((const float*)&v[j])[0]*sv);
    tmp[4*j+1] = __float2bfloat16(((const float*)&v[j])[1]*sv);
    tmp[4*j+2] = __float2bfloat16(((const float*)&v[j])[2]*sv);
    tmp[4*j+3] = __float2bfloat16(((const float*)&v[j])[3]*sv);
  }
  *(float4*)&T[i][x0]     = *(const float4*)&tmp[0];
  *(float4*)&T[i][x0 + 8] = *(const float4*)&tmp[8];

  const float4 z4 = make_float4(0.f, 0.f, 0.f, 0.f);
  if (t < 16) {
    const int side = t >> 3, j = t & 7;
    float4* hz = (float4*)(Xm + (((size_t)(b*66 + (y+1))*66 + side*65)*512 + ic0 + j*8));
    *hz = z4;
  }
  if (y == 0) {
    for (int idx = t; idx < 528; idx += 256) {
      const int px = idx >> 3, j = idx & 7;
      float4* hz = (float4*)(Xm + (((size_t)(b*66 + 0)*66 + px)*512 + ic0 + j*8));
      *hz = z4;
    }
  }
  if (y == 63) {
    for (int idx = t; idx < 528; idx += 256) {
      const int px = idx >> 3, j = idx & 7;
      float4* hz = (float4*)(Xm + (((size_t)(b*66 + 65)*66 + px)*512 + ic0 + j*8));
      *hz = z4;
    }
  }

  __syncthreads();
  const int p = t >> 2;
  __hip_bfloat16 o16[16];
  #pragma unroll
  for (int cc = 0; cc < 16; ++cc) o16[cc] = T[q*16 + cc][p];
  __hip_bfloat16* dst = Xm + (((size_t)(b*66 + (y+1))*66 + (p+1))*512 + ic0 + q*16);
  *(float4*)dst       = *(const float4*)&o16[0];
  *(float4*)(dst + 8) = *(const float4*)&o16[8];
}

// ---------------------------------------------------------------------------
// K4: conv as implicit GEMM, BK=32, block tile 128x256, 4 waves (1M x 4N),
// wave tile 128x64, 16x16x32 MFMA.  LDS = 48KB -> TWO independent blocks
// per CU (independent barriers; m114 co-scheduling hides each other's
// sync/drain — the ~1800cyc/tile residual no schedule probe could remove
// within one barrier-locked block).  K=32 = full 64B LDS row per frag ->
// dense contiguous 1KB per ds_read_b128 -> bank-uniform with LINEAR layout
// (no swizzle anywhere).  Read ratio stays minimal (12 reads / 32 MFMA).
// Hoisted SALU staging addresses; 1 VMC(0) + 1 barrier per K-tile.
// ---------------------------------------------------------------------------
#define VMC(n) asm volatile("s_waitcnt vmcnt(" #n ")" ::: "memory")

__global__ __launch_bounds__(256, 2) void k_conv(
    const __hip_bfloat16* __restrict__ Wb,   // [9][512][512]
    const __hip_bfloat16* __restrict__ Xm,   // [16][66][66][512]
    const float* __restrict__ demod,         // [16][512]
    float* __restrict__ out)                 // [16][512][64][64]
{
  __shared__ __hip_bfloat16 lds[2][12288];   // [buf][ A:0..8KB | B:8..24KB ]

  const int orig = blockIdx.x;
  const int swz = (orig & 7)*128 + (orig >> 3);   // bijective (1024%8==0)
  const int b  = swz >> 6;
  const int mt = (swz >> 4) & 3;
  const int nt = swz & 15;
  const int o0 = mt*128, y0 = nt*4;

  const int t = threadIdx.x;
  const int l = t & 63;
  const int w = t >> 6;        // 0..3

  const char* WbC = (const char*)Wb;
  const char* XmC = (const char*)Xm;

  // ---- staging per-thread invariant offsets (all linear) ----
  int aoff[2], boff[4];
  #pragma unroll
  for (int it = 0; it < 2; ++it)
    aoff[it] = (o0 + it*64 + (t >> 2))*1024 + (t & 3)*16;
  #pragma unroll
  for (int it = 0; it < 4; ++it)
    boff[it] = ((b*66 + y0 + 1 + it)*66 + (t >> 2) + 1)*1024 + (t & 3)*16;

  // ---- frag-read constants (16x16x32: row=l&15, k-quarter=l>>4) ----
  const int fr  = l & 15;
  const int kq  = (l >> 4) << 4;

  // stage K-tile tau (kk = tau>>4, chunk = tau&15) into buf bfi: 6 glds
  #define STAGE(tau, bfi) do { \
    const int ua_ = ((tau) >> 4)*524288 + (((tau) & 15) << 6); \
    const int kk_ = (tau) >> 4; \
    const int dy_ = kk_/3 - 1, dx_ = kk_ - (kk_/3)*3 - 1; \
    const int ub_ = (dy_*66 + dx_)*1024 + (((tau) & 15) << 6); \
    _Pragma("unroll") \
    for (int it_ = 0; it_ < 2; ++it_) \
      __builtin_amdgcn_global_load_lds( \
        (__attribute__((address_space(1))) void*)(WbC + ua_ + aoff[it_]), \
        (__attribute__((address_space(3))) void*)((char*)&lds[bfi][0] + it_*4096 + w*1024), \
        16, 0, 0); \
    _Pragma("unroll") \
    for (int it_ = 0; it_ < 4; ++it_) \
      __builtin_amdgcn_global_load_lds( \
        (__attribute__((address_space(1))) void*)(XmC + ub_ + boff[it_]), \
        (__attribute__((address_space(3))) void*)((char*)&lds[bfi][0] + 8192 + it_*4096 + w*1024), \
        16, 0, 0); \
  } while(0)

  // compute K-tile from buf bfi: 12 ds_read_b128 + 32 MFMA
  #define COMPUTE(bfi) do { \
    const char* Ab_ = (const char*)&lds[bfi][0]; \
    const char* Bb_ = Ab_ + 8192; \
    bf16x8 a_[8], b_[4]; \
    _Pragma("unroll") \
    for (int mi_ = 0; mi_ < 8; ++mi_) \
      a_[mi_] = *(const bf16x8*)(Ab_ + (mi_*16 + fr)*64 + kq); \
    _Pragma("unroll") \
    for (int ni_ = 0; ni_ < 4; ++ni_) \
      b_[ni_] = *(const bf16x8*)(Bb_ + (w*64 + ni_*16 + fr)*64 + kq); \
    _Pragma("unroll") \
    for (int mi_ = 0; mi_ < 8; ++mi_) \
      _Pragma("unroll") \
      for (int ni_ = 0; ni_ < 4; ++ni_) \
        acc[mi_][ni_] = __builtin_amdgcn_mfma_f32_16x16x32_bf16( \
            a_[mi_], b_[ni_], acc[mi_][ni_], 0, 0, 0); \
  } while(0)

  f32x4 acc[8][4] = {};

  // prologue: tile 0 -> buf 0
  STAGE(0, 0);
  VMC(0);
  __builtin_amdgcn_s_barrier();

  #pragma unroll 2
  for (int tau = 0; tau < 143; ++tau) {
    const int p = tau & 1;
    STAGE(tau + 1, p ^ 1);
    COMPUTE(p);
    VMC(0);
    __builtin_amdgcn_s_barrier();
  }
  COMPUTE(1);   // tau = 143 (143&1 = 1)

  // epilogue: demod scale, NCHW fp32 store.
  // C/D 16x16 layout: col=l&15 (N), row=(l>>4)*4 + j (M)  [m89/m91].
  #pragma unroll
  for (int mi = 0; mi < 8; ++mi) {
    const int om = o0 + mi*16 + ((l >> 4) << 2);
    const f32x4 dm = *(const f32x4*)(demod + b*512 + om);
    #pragma unroll
    for (int ni = 0; ni < 4; ++ni) {
      const int nc = w*64 + ni*16 + (l & 15);
      const int y = y0 + (nc >> 6), xx = nc & 63;
      float* op = out + (size_t)(b*512 + om)*4096 + y*64 + xx;
      #pragma unroll
      for (int j = 0; j < 4; ++j)
        op[(size_t)j*4096] = acc[mi][ni][j] * dm[j];
    }
  }
  #undef COMPUTE
  #undef STAGE
}

// ---------------------------------------------------------------------------
extern "C" void kernel_launch(void* const* d_in, const int* in_sizes, int n_in,
                              void* d_out, int out_size, void* d_ws, size_t ws_size,
                              hipStream_t stream)
{
  const float* x      = (const float*)d_in[0];
  const float* style  = (const float*)d_in[1];
  const float* weight = (const float*)d_in[2];
  const float* mod_w  = (const float*)d_in[3];
  const float* mod_b  = (const float*)d_in[4];
  float* out = (float*)d_out;

  char* ws = (char*)d_ws;
  float* s            = (float*)(ws);                  //  32 KB  [16][512]
  float* demod        = (float*)(ws + 32768);          //  32 KB  [16][512]
  float* w2           = (float*)(ws + 65536);          //   1 MB  [512][512]
  __hip_bfloat16* Wb  = (__hip_bfloat16*)(ws + 1114112);   // 4.5 MB [9][512][512]
  __hip_bfloat16* Xm  = (__hip_bfloat16*)(ws + 5832704);   // 71.4 MB [16][66][66][512]

  k_style <<<128,  64, 0, stream>>>(style, mod_w, mod_b, s);
  k_weight<<<512, 256, 0, stream>>>(weight, w2, Wb);
  k_demod <<<128,  64, 0, stream>>>(s, w2, demod);
  k_xm    <<<8192, 256, 0, stream>>>(x, s, Xm);
  k_conv  <<<1024, 256, 0, stream>>>(Wb, Xm, demod, out);
}

// Round 18
// 369.284 us; speedup vs baseline: 1.0013x; 1.0013x over previous
//
#include <hip/hip_runtime.h>
#include <hip/hip_bf16.h>
#include <cstdint>
#include <cstddef>

typedef __bf16 bf16x8 __attribute__((ext_vector_type(8)));
typedef float f32x4 __attribute__((ext_vector_type(4)));

#define MOD_SCALE 1.4731391e-02f   // 1/sqrt(512*9)
#define EPSF 1e-8f

// ---------------------------------------------------------------------------
// K1: s[b][i] = dot(style[b], mod_w[i]) + mod_b[i]   (grid 16b x 8ig, 64 thr)
// ---------------------------------------------------------------------------
__global__ __launch_bounds__(64) void k_style(
    const float* __restrict__ style, const float* __restrict__ mod_w,
    const float* __restrict__ mod_b, float* __restrict__ s)
{
  __shared__ float st[512];
  const int b = blockIdx.x >> 3, ig = blockIdx.x & 7;
  const int t = threadIdx.x;
  for (int k = t; k < 512; k += 64) st[k] = style[b*512 + k];
  __syncthreads();
  const int i = ig*64 + t;
  const float4* mw = (const float4*)(mod_w + (size_t)i*512);
  float acc = 0.f;
  #pragma unroll 8
  for (int j = 0; j < 128; ++j) {
    float4 v = mw[j];
    acc += v.x*st[4*j] + v.y*st[4*j+1] + v.z*st[4*j+2] + v.w*st[4*j+3];
  }
  s[b*512 + i] = acc + mod_b[i];
}

// ---------------------------------------------------------------------------
// K2: w2[o][i] = sum_kk weight^2 ; Wb[kk][o][i] = bf16(SCALE*weight)
// ---------------------------------------------------------------------------
__global__ __launch_bounds__(256) void k_weight(
    const float* __restrict__ weight, float* __restrict__ w2,
    __hip_bfloat16* __restrict__ Wb)
{
  const int o = blockIdx.x, t = threadIdx.x;
  #pragma unroll
  for (int h = 0; h < 2; ++h) {
    const int i = t + h*256;
    const float* wp = weight + ((size_t)o*512 + i)*9;
    float sq = 0.f;
    #pragma unroll
    for (int kk = 0; kk < 9; ++kk) {
      float v = wp[kk];
      sq += v*v;
      Wb[((size_t)kk*512 + o)*512 + i] = __float2bfloat16(v * MOD_SCALE);
    }
    w2[(size_t)o*512 + i] = sq;
  }
}

// ---------------------------------------------------------------------------
// K2b: demod[b][o] = rsqrt(...)   (grid 16b x 8og, 64 thr)
// ---------------------------------------------------------------------------
__global__ __launch_bounds__(64) void k_demod(
    const float* __restrict__ s, const float* __restrict__ w2,
    float* __restrict__ demod)
{
  __shared__ float s2[512];
  const int b = blockIdx.x >> 3, og = blockIdx.x & 7;
  const int t = threadIdx.x;
  for (int k = t; k < 512; k += 64) { float a = s[b*512 + k]; s2[k] = a*a; }
  __syncthreads();
  const int o = og*64 + t;
  const float4* wp = (const float4*)(w2 + (size_t)o*512);
  float acc = 0.f;
  #pragma unroll 8
  for (int j = 0; j < 128; ++j) {
    float4 v = wp[j];
    acc += v.x*s2[4*j] + v.y*s2[4*j+1] + v.z*s2[4*j+2] + v.w*s2[4*j+3];
  }
  demod[b*512 + o] = rsqrtf(MOD_SCALE*MOD_SCALE*acc + EPSF);
}

// ---------------------------------------------------------------------------
// K3: Xm[b][py][px][i] = bf16(s[b][i]*x[b][i][py-1][px-1]); writes own halo.
// ---------------------------------------------------------------------------
__global__ __launch_bounds__(256) void k_xm(
    const float* __restrict__ x, const float* __restrict__ s,
    __hip_bfloat16* __restrict__ Xm)
{
  __shared__ __hip_bfloat16 T[64][72];   // [ch][px], stride 144B
  const int bid = blockIdx.x;
  const int cb = bid & 7, y = (bid >> 3) & 63, b = bid >> 9;
  const int ic0 = cb*64;
  const int t = threadIdx.x;
  const int i = t >> 2;            // ch 0..63
  const int q = t & 3;             // px quarter
  const int x0 = q*16;
  const float sv = s[b*512 + ic0 + i];
  const float4* xp = (const float4*)(x + (size_t)(b*512 + ic0 + i)*4096 + y*64 + x0);
  float4 v[4] = {xp[0], xp[1], xp[2], xp[3]};
  __hip_bfloat16 tmp[16];
  #pragma unroll
  for (int j = 0; j < 4; ++j) {
    tmp[4*j+0] = __float2bfloat16(((const float*)&v[j])[0]*sv);
    tmp[4*j+1] = __float2bfloat16(((const float*)&v[j])[1]*sv);
    tmp[4*j+2] = __float2bfloat16(((const float*)&v[j])[2]*sv);
    tmp[4*j+3] = __float2bfloat16(((const float*)&v[j])[3]*sv);
  }
  *(float4*)&T[i][x0]     = *(const float4*)&tmp[0];
  *(float4*)&T[i][x0 + 8] = *(const float4*)&tmp[8];

  const float4 z4 = make_float4(0.f, 0.f, 0.f, 0.f);
  if (t < 16) {
    const int side = t >> 3, j = t & 7;
    float4* hz = (float4*)(Xm + (((size_t)(b*66 + (y+1))*66 + side*65)*512 + ic0 + j*8));
    *hz = z4;
  }
  if (y == 0) {
    for (int idx = t; idx < 528; idx += 256) {
      const int px = idx >> 3, j = idx & 7;
      float4* hz = (float4*)(Xm + (((size_t)(b*66 + 0)*66 + px)*512 + ic0 + j*8));
      *hz = z4;
    }
  }
  if (y == 63) {
    for (int idx = t; idx < 528; idx += 256) {
      const int px = idx >> 3, j = idx & 7;
      float4* hz = (float4*)(Xm + (((size_t)(b*66 + 65)*66 + px)*512 + ic0 + j*8));
      *hz = z4;
    }
  }

  __syncthreads();
  const int p = t >> 2;
  __hip_bfloat16 o16[16];
  #pragma unroll
  for (int cc = 0; cc < 16; ++cc) o16[cc] = T[q*16 + cc][p];
  __hip_bfloat16* dst = Xm + (((size_t)(b*66 + (y+1))*66 + (p+1))*512 + ic0 + q*16);
  *(float4*)dst       = *(const float4*)&o16[0];
  *(float4*)(dst + 8) = *(const float4*)&o16[8];
}

// ---------------------------------------------------------------------------
// K4: R17 structure (BK=32, block tile 128x256, 4 waves, 2 blocks/CU for
// cross-block TLP) + CONFLICT-FREE 64B-row swizzle: col ^= ((row>>1)&3)<<4.
// R17's linear layout was an 8-way conflict (64B row stride = banks repeat
// every 2 rows; 16 lanes -> 2 quad-sets).  The swizzle makes quad(fr) =
// (4*fr + ((fr>>1)&3)) mod 8 sweep all 8 quads twice -> 2-way = free.
// Applied on stage SOURCE col and frag-read col (same involution, rule #21);
// glds LDS dest stays linear.  R17's measured behavior already implied ~2x
// cross-block overlap despite conflicts — this un-inflates the LDS term.
// ---------------------------------------------------------------------------
#define VMC(n) asm volatile("s_waitcnt vmcnt(" #n ")" ::: "memory")

__global__ __launch_bounds__(256, 2) void k_conv(
    const __hip_bfloat16* __restrict__ Wb,   // [9][512][512]
    const __hip_bfloat16* __restrict__ Xm,   // [16][66][66][512]
    const float* __restrict__ demod,         // [16][512]
    float* __restrict__ out)                 // [16][512][64][64]
{
  __shared__ __hip_bfloat16 lds[2][12288];   // [buf][ A:0..8KB | B:8..24KB ]

  const int orig = blockIdx.x;
  const int swz = (orig & 7)*128 + (orig >> 3);   // bijective (1024%8==0)
  const int b  = swz >> 6;
  const int mt = (swz >> 4) & 3;
  const int nt = swz & 15;
  const int o0 = mt*128, y0 = nt*4;

  const int t = threadIdx.x;
  const int l = t & 63;
  const int w = t >> 6;        // 0..3

  const char* WbC = (const char*)Wb;
  const char* XmC = (const char*)Xm;

  // ---- staging per-thread invariant offsets; swizzle folded into source:
  //      col' = ((t&3)<<4) ^ (((t>>3)&3)<<4)  (row = it*64 + (t>>2)) ----
  const int scol = ((t & 3) << 4) ^ (((t >> 3) & 3) << 4);
  int aoff[2], boff[4];
  #pragma unroll
  for (int it = 0; it < 2; ++it)
    aoff[it] = (o0 + it*64 + (t >> 2))*1024 + scol;
  #pragma unroll
  for (int it = 0; it < 4; ++it)
    boff[it] = ((b*66 + y0 + 1 + it)*66 + (t >> 2) + 1)*1024 + scol;

  // ---- frag-read constants (16x16x32: row=l&15, k-quarter=l>>4) ----
  const int fr  = l & 15;
  const int kc  = (((l >> 4) << 4)) ^ (((fr >> 1) & 3) << 4);  // swizzled col

  // stage K-tile tau (kk = tau>>4, chunk = tau&15) into buf bfi: 6 glds
  #define STAGE(tau, bfi) do { \
    const int ua_ = ((tau) >> 4)*524288 + (((tau) & 15) << 6); \
    const int kk_ = (tau) >> 4; \
    const int dy_ = kk_/3 - 1, dx_ = kk_ - (kk_/3)*3 - 1; \
    const int ub_ = (dy_*66 + dx_)*1024 + (((tau) & 15) << 6); \
    _Pragma("unroll") \
    for (int it_ = 0; it_ < 2; ++it_) \
      __builtin_amdgcn_global_load_lds( \
        (__attribute__((address_space(1))) void*)(WbC + ua_ + aoff[it_]), \
        (__attribute__((address_space(3))) void*)((char*)&lds[bfi][0] + it_*4096 + w*1024), \
        16, 0, 0); \
    _Pragma("unroll") \
    for (int it_ = 0; it_ < 4; ++it_) \
      __builtin_amdgcn_global_load_lds( \
        (__attribute__((address_space(1))) void*)(XmC + ub_ + boff[it_]), \
        (__attribute__((address_space(3))) void*)((char*)&lds[bfi][0] + 8192 + it_*4096 + w*1024), \
        16, 0, 0); \
  } while(0)

  // compute K-tile from buf bfi: 12 ds_read_b128 + 32 MFMA
  #define COMPUTE(bfi) do { \
    const char* Ab_ = (const char*)&lds[bfi][0]; \
    const char* Bb_ = Ab_ + 8192; \
    bf16x8 a_[8], b_[4]; \
    _Pragma("unroll") \
    for (int mi_ = 0; mi_ < 8; ++mi_) \
      a_[mi_] = *(const bf16x8*)(Ab_ + (mi_*16 + fr)*64 + kc); \
    _Pragma("unroll") \
    for (int ni_ = 0; ni_ < 4; ++ni_) \
      b_[ni_] = *(const bf16x8*)(Bb_ + (w*64 + ni_*16 + fr)*64 + kc); \
    _Pragma("unroll") \
    for (int mi_ = 0; mi_ < 8; ++mi_) \
      _Pragma("unroll") \
      for (int ni_ = 0; ni_ < 4; ++ni_) \
        acc[mi_][ni_] = __builtin_amdgcn_mfma_f32_16x16x32_bf16( \
            a_[mi_], b_[ni_], acc[mi_][ni_], 0, 0, 0); \
  } while(0)

  f32x4 acc[8][4] = {};

  // prologue: tile 0 -> buf 0
  STAGE(0, 0);
  VMC(0);
  __builtin_amdgcn_s_barrier();

  #pragma unroll 2
  for (int tau = 0; tau < 143; ++tau) {
    const int p = tau & 1;
    STAGE(tau + 1, p ^ 1);
    COMPUTE(p);
    VMC(0);
    __builtin_amdgcn_s_barrier();
  }
  COMPUTE(1);   // tau = 143

  // epilogue: demod scale, NCHW fp32 store.
  // C/D 16x16 layout: col=l&15 (N), row=(l>>4)*4 + j (M)  [m89/m91].
  #pragma unroll
  for (int mi = 0; mi < 8; ++mi) {
    const int om = o0 + mi*16 + ((l >> 4) << 2);
    const f32x4 dm = *(const f32x4*)(demod + b*512 + om);
    #pragma unroll
    for (int ni = 0; ni < 4; ++ni) {
      const int nc = w*64 + ni*16 + (l & 15);
      const int y = y0 + (nc >> 6), xx = nc & 63;
      float* op = out + (size_t)(b*512 + om)*4096 + y*64 + xx;
      #pragma unroll
      for (int j = 0; j < 4; ++j)
        op[(size_t)j*4096] = acc[mi][ni][j] * dm[j];
    }
  }
  #undef COMPUTE
  #undef STAGE
}

// ---------------------------------------------------------------------------
extern "C" void kernel_launch(void* const* d_in, const int* in_sizes, int n_in,
                              void* d_out, int out_size, void* d_ws, size_t ws_size,
                              hipStream_t stream)
{
  const float* x      = (const float*)d_in[0];
  const float* style  = (const float*)d_in[1];
  const float* weight = (const float*)d_in[2];
  const float* mod_w  = (const float*)d_in[3];
  const float* mod_b  = (const float*)d_in[4];
  float* out = (float*)d_out;

  char* ws = (char*)d_ws;
  float* s            = (float*)(ws);                  //  32 KB  [16][512]
  float* demod        = (float*)(ws + 32768);          //  32 KB  [16][512]
  float* w2           = (float*)(ws + 65536);          //   1 MB  [512][512]
  __hip_bfloat16* Wb  = (__hip_bfloat16*)(ws + 1114112);   // 4.5 MB [9][512][512]
  __hip_bfloat16* Xm  = (__hip_bfloat16*)(ws + 5832704);   // 71.4 MB [16][66][66][512]

  k_style <<<128,  64, 0, stream>>>(style, mod_w, mod_b, s);
  k_weight<<<512, 256, 0, stream>>>(weight, w2, Wb);
  k_demod <<<128,  64, 0, stream>>>(s, w2, demod);
  k_xm    <<<8192, 256, 0, stream>>>(x, s, Xm);
  k_conv  <<<1024, 256, 0, stream>>>(Wb, Xm, demod, out);
}

// Round 19
// 326.877 us; speedup vs baseline: 1.1312x; 1.1297x over previous
//
#include <hip/hip_runtime.h>
#include <hip/hip_bf16.h>
#include <cstdint>
#include <cstddef>

typedef __bf16 bf16x8 __attribute__((ext_vector_type(8)));
typedef float f32x4 __attribute__((ext_vector_type(4)));

#define MOD_SCALE 1.4731391e-02f   // 1/sqrt(512*9)
#define EPSF 1e-8f

// ---------------------------------------------------------------------------
// K1: s[b][i] = dot(style[b], mod_w[i]) + mod_b[i]   (grid 16b x 8ig, 64 thr)
// ---------------------------------------------------------------------------
__global__ __launch_bounds__(64) void k_style(
    const float* __restrict__ style, const float* __restrict__ mod_w,
    const float* __restrict__ mod_b, float* __restrict__ s)
{
  __shared__ float st[512];
  const int b = blockIdx.x >> 3, ig = blockIdx.x & 7;
  const int t = threadIdx.x;
  for (int k = t; k < 512; k += 64) st[k] = style[b*512 + k];
  __syncthreads();
  const int i = ig*64 + t;
  const float4* mw = (const float4*)(mod_w + (size_t)i*512);
  float acc = 0.f;
  #pragma unroll 8
  for (int j = 0; j < 128; ++j) {
    float4 v = mw[j];
    acc += v.x*st[4*j] + v.y*st[4*j+1] + v.z*st[4*j+2] + v.w*st[4*j+3];
  }
  s[b*512 + i] = acc + mod_b[i];
}

// ---------------------------------------------------------------------------
// K2: w2[o][i] = sum_kk weight^2 ; Wb[kk][o][i] = bf16(SCALE*weight)
// ---------------------------------------------------------------------------
__global__ __launch_bounds__(256) void k_weight(
    const float* __restrict__ weight, float* __restrict__ w2,
    __hip_bfloat16* __restrict__ Wb)
{
  const int o = blockIdx.x, t = threadIdx.x;
  #pragma unroll
  for (int h = 0; h < 2; ++h) {
    const int i = t + h*256;
    const float* wp = weight + ((size_t)o*512 + i)*9;
    float sq = 0.f;
    #pragma unroll
    for (int kk = 0; kk < 9; ++kk) {
      float v = wp[kk];
      sq += v*v;
      Wb[((size_t)kk*512 + o)*512 + i] = __float2bfloat16(v * MOD_SCALE);
    }
    w2[(size_t)o*512 + i] = sq;
  }
}

// ---------------------------------------------------------------------------
// K2b: demod[b][o] = rsqrt(...)   (grid 16b x 8og, 64 thr)
// ---------------------------------------------------------------------------
__global__ __launch_bounds__(64) void k_demod(
    const float* __restrict__ s, const float* __restrict__ w2,
    float* __restrict__ demod)
{
  __shared__ float s2[512];
  const int b = blockIdx.x >> 3, og = blockIdx.x & 7;
  const int t = threadIdx.x;
  for (int k = t; k < 512; k += 64) { float a = s[b*512 + k]; s2[k] = a*a; }
  __syncthreads();
  const int o = og*64 + t;
  const float4* wp = (const float4*)(w2 + (size_t)o*512);
  float acc = 0.f;
  #pragma unroll 8
  for (int j = 0; j < 128; ++j) {
    float4 v = wp[j];
    acc += v.x*s2[4*j] + v.y*s2[4*j+1] + v.z*s2[4*j+2] + v.w*s2[4*j+3];
  }
  demod[b*512 + o] = rsqrtf(MOD_SCALE*MOD_SCALE*acc + EPSF);
}

// ---------------------------------------------------------------------------
// K3: Xm[b][py][px][i] = bf16(s[b][i]*x[b][i][py-1][px-1]); writes own halo.
// ---------------------------------------------------------------------------
__global__ __launch_bounds__(256) void k_xm(
    const float* __restrict__ x, const float* __restrict__ s,
    __hip_bfloat16* __restrict__ Xm)
{
  __shared__ __hip_bfloat16 T[64][72];   // [ch][px], stride 144B
  const int bid = blockIdx.x;
  const int cb = bid & 7, y = (bid >> 3) & 63, b = bid >> 9;
  const int ic0 = cb*64;
  const int t = threadIdx.x;
  const int i = t >> 2;            // ch 0..63
  const int q = t & 3;             // px quarter
  const int x0 = q*16;
  const float sv = s[b*512 + ic0 + i];
  const float4* xp = (const float4*)(x + (size_t)(b*512 + ic0 + i)*4096 + y*64 + x0);
  float4 v[4] = {xp[0], xp[1], xp[2], xp[3]};
  __hip_bfloat16 tmp[16];
  #pragma unroll
  for (int j = 0; j < 4; ++j) {
    tmp[4*j+0] = __float2bfloat16(((const float*)&v[j])[0]*sv);
    tmp[4*j+1] = __float2bfloat16(((const float*)&v[j])[1]*sv);
    tmp[4*j+2] = __float2bfloat16(((const float*)&v[j])[2]*sv);
    tmp[4*j+3] = __float2bfloat16(((const float*)&v[j])[3]*sv);
  }
  *(float4*)&T[i][x0]     = *(const float4*)&tmp[0];
  *(float4*)&T[i][x0 + 8] = *(const float4*)&tmp[8];

  const float4 z4 = make_float4(0.f, 0.f, 0.f, 0.f);
  if (t < 16) {
    const int side = t >> 3, j = t & 7;
    float4* hz = (float4*)(Xm + (((size_t)(b*66 + (y+1))*66 + side*65)*512 + ic0 + j*8));
    *hz = z4;
  }
  if (y == 0) {
    for (int idx = t; idx < 528; idx += 256) {
      const int px = idx >> 3, j = idx & 7;
      float4* hz = (float4*)(Xm + (((size_t)(b*66 + 0)*66 + px)*512 + ic0 + j*8));
      *hz = z4;
    }
  }
  if (y == 63) {
    for (int idx = t; idx < 528; idx += 256) {
      const int px = idx >> 3, j = idx & 7;
      float4* hz = (float4*)(Xm + (((size_t)(b*66 + 65)*66 + px)*512 + ic0 + j*8));
      *hz = z4;
    }
  }

  __syncthreads();
  const int p = t >> 2;
  __hip_bfloat16 o16[16];
  #pragma unroll
  for (int cc = 0; cc < 16; ++cc) o16[cc] = T[q*16 + cc][p];
  __hip_bfloat16* dst = Xm + (((size_t)(b*66 + (y+1))*66 + (p+1))*512 + ic0 + q*16);
  *(float4*)dst       = *(const float4*)&o16[0];
  *(float4*)(dst + 8) = *(const float4*)&o16[8];
}

// ---------------------------------------------------------------------------
// K4: best verified k_conv (R16, 277 us): 256x256 tile, BK=64, 8 waves,
// 16x16x32 MFMA at minimal 24 reads/wave/K-tile, R2/R3 conflict-free XOR
// layout, hoisted SALU staging addresses, m201 wait discipline, XCD swizzle.
// Measured: slot ~= LDS-pipe term (192 b128-reads + 64KB glds-writes) with
// ~13% MFMA overlap; LDS-throughput-bound with 3x operand duplication —
// structural floor of this geometry (128x128 waves spill; LDS-bypass and
// 2-block TLP variants measured slower).
// ---------------------------------------------------------------------------
#define VMC(n) asm volatile("s_waitcnt vmcnt(" #n ")" ::: "memory")
#define LGKM0() do { \
    asm volatile("s_waitcnt lgkmcnt(0)" ::: "memory"); \
    __builtin_amdgcn_sched_barrier(0); \
  } while(0)

__global__ __launch_bounds__(512, 2) void k_conv(
    const __hip_bfloat16* __restrict__ Wb,   // [9][512][512]
    const __hip_bfloat16* __restrict__ Xm,   // [16][66][66][512]
    const float* __restrict__ demod,         // [16][512]
    float* __restrict__ out)                 // [16][512][64][64]
{
  __shared__ __hip_bfloat16 lds[2][2][16384];   // [buf][A=0/B=1][256*64]

  const int orig = blockIdx.x;
  const int swz = (orig & 7)*64 + (orig >> 3);   // bijective XCD swizzle (512%8==0)
  const int b  = swz >> 5;
  const int nt = (swz & 31) >> 1;
  const int mt = swz & 1;
  const int o0 = mt*256, y0 = nt*4;

  const int tid = threadIdx.x;
  const int l = tid & 63;
  const int w = tid >> 6;
  const int wm = w >> 2;       // 0..1
  const int wn = w & 3;        // 0..3

  // ---- staging: per-thread invariant offsets (XOR swizzle folded) ----
  const int srow = tid >> 3;
  const int scol = (((tid & 7) ^ (srow & 7)) << 4);
  const char* WbC = (const char*)Wb;
  const char* XmC = (const char*)Xm;

  int aoff[2], boff[2], ldst[2];
  #pragma unroll
  for (int it = 0; it < 2; ++it) {
    aoff[it] = (o0 + it*64 + srow)*1024 + scol;
    boff[it] = (((b*66 + y0 + 1 + it)*66) + srow + 1)*1024 + scol;
    ldst[it] = it*8192 + w*1024;
  }

  // ---- frag-read constants (16x16x32 frag: row=l&15, k-quarter=l>>4) ----
  const int frow = l & 15;
  const int sB   = (l & 7) << 4;
  const int kq   = (l >> 4) << 4;
  const int kc0  = (kq)      ^ sB;     // ks = 0
  const int kc1  = (64 | kq) ^ sB;     // ks = 1
  const int aBase = (wm*64 + frow)*128;
  const int bBase = (wn*32 + frow)*128;

  #define STAGE_A(tau, h, bfi) do { \
    const int u_ = ((tau) >> 3)*524288 + (h)*131072 + (((tau) & 7) << 7); \
    _Pragma("unroll") \
    for (int it_ = 0; it_ < 2; ++it_) \
      __builtin_amdgcn_global_load_lds( \
        (__attribute__((address_space(1))) void*)(WbC + u_ + aoff[it_]), \
        (__attribute__((address_space(3))) void*)((char*)&lds[bfi][0][0] + (h)*16384 + ldst[it_]), \
        16, 0, 0); \
  } while(0)

  #define STAGE_B(tau, h, bfi) do { \
    const int kk_ = (tau) >> 3; \
    const int dy_ = kk_/3 - 1, dx_ = kk_ - (kk_/3)*3 - 1; \
    const int u_ = (((h)*2 + dy_)*66 + dx_)*1024 + (((tau) & 7) << 7); \
    _Pragma("unroll") \
    for (int it_ = 0; it_ < 2; ++it_) \
      __builtin_amdgcn_global_load_lds( \
        (__attribute__((address_space(1))) void*)(XmC + u_ + boff[it_]), \
        (__attribute__((address_space(3))) void*)((char*)&lds[bfi][1][0] + (h)*16384 + ldst[it_]), \
        16, 0, 0); \
  } while(0)

  // A quadrant: 4 m-frags x 2 ks = 8 x b128
  #define RD_A(Ab, MH, dst) do { \
    _Pragma("unroll") \
    for (int mi_ = 0; mi_ < 4; ++mi_) { \
      dst[mi_][0] = *(const bf16x8*)((Ab) + (MH)*16384 + aBase + mi_*2048 + kc0); \
      dst[mi_][1] = *(const bf16x8*)((Ab) + (MH)*16384 + aBase + mi_*2048 + kc1); \
    } \
  } while(0)

  // B quadrant: 2 n-frags x 2 ks = 4 x b128
  #define RD_B(Bb, NH, dst) do { \
    _Pragma("unroll") \
    for (int ni_ = 0; ni_ < 2; ++ni_) { \
      dst[ni_][0] = *(const bf16x8*)((Bb) + (NH)*16384 + bBase + ni_*2048 + kc0); \
      dst[ni_][1] = *(const bf16x8*)((Bb) + (NH)*16384 + bBase + ni_*2048 + kc1); \
    } \
  } while(0)

  // quadrant MFMA: 2 ks x (4 m x 2 n) = 16 indep-within-ks 16x16x32 MFMAs
  #define MFMAQ(MH, dstA, NH, dstB) do { \
    _Pragma("unroll") \
    for (int ks_ = 0; ks_ < 2; ++ks_) \
      _Pragma("unroll") \
      for (int mi_ = 0; mi_ < 4; ++mi_) \
        _Pragma("unroll") \
        for (int ni_ = 0; ni_ < 2; ++ni_) \
          acc[(MH)*4+mi_][(NH)*2+ni_] = __builtin_amdgcn_mfma_f32_16x16x32_bf16( \
              dstA[mi_][ks_], dstB[ni_][ks_], acc[(MH)*4+mi_][(NH)*2+ni_], 0, 0, 0); \
  } while(0)

  // One K-tile = 4 phases: P1:Q00(rd A0,B0) P2:Q01(rd B1) P3:Q11(rd A1) P4:Q10.
  #define TILE(BFI, S1, S2, S3, S4, VM1, VM4) do { \
    const char* Ab_ = (const char*)&lds[BFI][0][0]; \
    const char* Bb_ = (const char*)&lds[BFI][1][0]; \
    bf16x8 a0_[4][2], a1_[4][2], b0_[2][2], b1_[2][2]; \
    /* P1 */ \
    RD_A(Ab_, 0, a0_); RD_B(Bb_, 0, b0_); \
    S1; \
    __builtin_amdgcn_s_barrier(); \
    LGKM0(); \
    __builtin_amdgcn_s_setprio(1); MFMAQ(0, a0_, 0, b0_); __builtin_amdgcn_s_setprio(0); \
    VM1; \
    __builtin_amdgcn_s_barrier(); \
    /* P2 */ \
    RD_B(Bb_, 1, b1_); \
    S2; \
    __builtin_amdgcn_s_barrier(); \
    LGKM0(); \
    __builtin_amdgcn_s_setprio(1); MFMAQ(0, a0_, 1, b1_); __builtin_amdgcn_s_setprio(0); \
    __builtin_amdgcn_s_barrier(); \
    /* P3 */ \
    RD_A(Ab_, 1, a1_); \
    S3; \
    __builtin_amdgcn_s_barrier(); \
    LGKM0(); \
    __builtin_amdgcn_s_setprio(1); MFMAQ(1, a1_, 1, b1_); __builtin_amdgcn_s_setprio(0); \
    __builtin_amdgcn_s_barrier(); \
    /* P4 */ \
    S4; \
    __builtin_amdgcn_s_barrier(); \
    __builtin_amdgcn_s_setprio(1); MFMAQ(1, a1_, 0, b0_); __builtin_amdgcn_s_setprio(0); \
    VM4; \
    __builtin_amdgcn_s_barrier(); \
  } while(0)

  f32x4 acc[8][4] = {};

  // prologue: tile0 complete + B(1,h0), A(1,h1); leave 2 half-tiles in flight
  STAGE_A(0, 0, 0); STAGE_A(0, 1, 0); STAGE_B(0, 0, 0); STAGE_B(0, 1, 0);
  STAGE_B(1, 0, 1); STAGE_A(1, 1, 1);
  VMC(4);
  __builtin_amdgcn_s_barrier();

  #pragma unroll 1
  for (int tt = 0; tt < 35; ++tt) {
    const int t = tt*2;
    TILE(0, STAGE_A(t+1,0,1), STAGE_B(t+1,1,1), STAGE_B(t+2,0,0), STAGE_A(t+2,1,0),
            VMC(6), VMC(6));
    TILE(1, STAGE_A(t+2,0,0), STAGE_B(t+2,1,0), STAGE_B(t+3,0,1), STAGE_A(t+3,1,1),
            VMC(6), VMC(6));
  }
  // tail: t=70,71
  TILE(0, STAGE_A(71,0,1), STAGE_B(71,1,1), (void)0, (void)0, VMC(6), VMC(2));
  TILE(1, (void)0, (void)0, (void)0, (void)0, VMC(0), (void)0);

  // epilogue: demod scale, NCHW fp32 store.
  // C/D 16x16 layout: col=l&15 (N), row=(l>>4)*4 + j (M)  [m89/m91].
  #pragma unroll
  for (int am = 0; am < 8; ++am) {
    const int om = o0 + (am >> 2)*128 + wm*64 + (am & 3)*16 + ((l >> 4) << 2);
    const f32x4 dm = *(const f32x4*)(demod + b*512 + om);
    #pragma unroll
    for (int nn = 0; nn < 4; ++nn) {
      const int nc = (nn >> 1)*128 + wn*32 + (nn & 1)*16 + (l & 15);
      const int y = y0 + (nc >> 6), xx = nc & 63;
      float* op = out + (size_t)(b*512 + om)*4096 + y*64 + xx;
      #pragma unroll
      for (int j = 0; j < 4; ++j)
        op[(size_t)j*4096] = acc[am][nn][j] * dm[j];
    }
  }
  #undef TILE
  #undef MFMAQ
  #undef RD_A
  #undef RD_B
  #undef STAGE_A
  #undef STAGE_B
}

// ---------------------------------------------------------------------------
extern "C" void kernel_launch(void* const* d_in, const int* in_sizes, int n_in,
                              void* d_out, int out_size, void* d_ws, size_t ws_size,
                              hipStream_t stream)
{
  const float* x      = (const float*)d_in[0];
  const float* style  = (const float*)d_in[1];
  const float* weight = (const float*)d_in[2];
  const float* mod_w  = (const float*)d_in[3];
  const float* mod_b  = (const float*)d_in[4];
  float* out = (float*)d_out;

  char* ws = (char*)d_ws;
  float* s            = (float*)(ws);                  //  32 KB  [16][512]
  float* demod        = (float*)(ws + 32768);          //  32 KB  [16][512]
  float* w2           = (float*)(ws + 65536);          //   1 MB  [512][512]
  __hip_bfloat16* Wb  = (__hip_bfloat16*)(ws + 1114112);   // 4.5 MB [9][512][512]
  __hip_bfloat16* Xm  = (__hip_bfloat16*)(ws + 5832704);   // 71.4 MB [16][66][66][512]

  k_style <<<128,  64, 0, stream>>>(style, mod_w, mod_b, s);
  k_weight<<<512, 256, 0, stream>>>(weight, w2, Wb);
  k_demod <<<128,  64, 0, stream>>>(s, w2, demod);
  k_xm    <<<8192, 256, 0, stream>>>(x, s, Xm);
  k_conv  <<<512,  512, 0, stream>>>(Wb, Xm, demod, out);
}